// Round 7
// baseline (35.818 us; speedup 1.0000x reference)
//
#include <hip/hip_runtime.h>

#define IN_F   4096
#define OUT_F  4096
#define BATCH  512
#define NCONN  64
#define BT     8       // batch rows per block
#define OGRP   512     // output features per block (1 per thread)
#define NTHR   512

typedef _Float16 h8 __attribute__((ext_vector_type(8)));

// ---------------- Kernel 1: connT[k][o] = conn[o][k] ----------------
__global__ __launch_bounds__(256) void connT_kernel(const int* __restrict__ conn,
                                                    int* __restrict__ connT) {
    __shared__ int tile[64][65];
    const int o0 = blockIdx.x * 64;
    const int tx = threadIdx.x & 63;
    const int ty = threadIdx.x >> 6;   // 0..3
#pragma unroll
    for (int r = 0; r < 16; ++r) {
        const int row = ty * 16 + r;                  // o-local
        tile[row][tx] = conn[(size_t)(o0 + row) * NCONN + tx];
    }
    __syncthreads();
#pragma unroll
    for (int r = 0; r < 16; ++r) {
        const int k = ty * 16 + r;
        connT[(size_t)k * OUT_F + o0 + tx] = tile[tx][k];
    }
}

// ---------------- Kernel 2: LDS-staged gather + reduce ----------------
// Block: 8 batch rows x 512 o's. Full x-slice (4096 j x 8 b) in LDS as fp16.
__global__ __launch_bounds__(NTHR, 4) void agg_kernel(const float* __restrict__ x,
                                                      const int* __restrict__ connT,
                                                      const int* __restrict__ opidx,
                                                      float* __restrict__ out) {
    __shared__ alignas(16) _Float16 xs[IN_F * BT];   // [j][b], 64 KB

    // grid = 512 blocks = 64 b-tiles x 8 o-groups. HW round-robins bid->XCD
    // (bid&7); make b-tile a function of XCD so the 8 o-group blocks sharing
    // a b-tile's x rows land on one XCD (staging reads become L2 hits).
    const int bid   = blockIdx.x;
    const int btile = (bid & 7) * 8 + (bid >> 6);    // 0..63
    const int og    = (bid >> 3) & 7;                // 0..7
    const int o0    = og * OGRP;
    const int b0    = btile * BT;
    const int t     = threadIdx.x;

    // ---- stage x slice -> LDS fp16, [j][b] ----
    // lane covers (b = t&7, j = it*64 + t>>3): ds_write banks = all 32, 2/bank.
    const int bb   = t & 7;
    const int joff = t >> 3;                         // 0..63
    const float* __restrict__ xrow = x + (size_t)(b0 + bb) * IN_F;
#pragma unroll 8
    for (int it = 0; it < 64; ++it) {
        const int j = it * 64 + joff;
        xs[j * BT + bb] = (_Float16)xrow[j];
    }
    __syncthreads();

    // ---- gather + reduce: one o per thread ----
    const int o = o0 + t;
    float s[8], mx[8], mn[8];
#pragma unroll
    for (int i = 0; i < 8; ++i) {
        s[i]  = 0.f;
        mx[i] = -__builtin_inff();
        mn[i] =  __builtin_inff();
    }

#pragma unroll 8
    for (int k = 0; k < NCONN; ++k) {
        const int j = connT[(size_t)k * OUT_F + o];          // lane-coalesced
        const h8 v = *reinterpret_cast<const h8*>(&xs[j * BT]);  // ds_read_b128
#pragma unroll
        for (int i = 0; i < 8; ++i) {
            const float f = (float)v[i];
            s[i] += f;
            mx[i] = fmaxf(mx[i], f);
            mn[i] = fminf(mn[i], f);
        }
    }

    // ---- epilogue: scalar NT stores, coalesced along o ----
    const int op = opidx[o];
    float* __restrict__ fwd  = out;                          // (B, OUT_F)
    float* __restrict__ outp = out + (size_t)BATCH * OUT_F;  // (B, 4, OUT_F)

#pragma unroll
    for (int i = 0; i < 8; ++i) {
        const float ss = s[i];
        const float mm = ss * 0.015625f;
        const float hx = mx[i];
        const float ln = mn[i];
        const float fw = (op == 0) ? mm : (op == 1) ? ss : (op == 2) ? hx : ln;
        const size_t rowO = (size_t)(b0 + i) * (4 * OUT_F) + o;
        __builtin_nontemporal_store(fw, fwd + (size_t)(b0 + i) * OUT_F + o);
        __builtin_nontemporal_store(mm, outp + rowO);
        __builtin_nontemporal_store(ss, outp + rowO + OUT_F);
        __builtin_nontemporal_store(hx, outp + rowO + 2 * OUT_F);
        __builtin_nontemporal_store(ln, outp + rowO + 3 * OUT_F);
    }
}

extern "C" void kernel_launch(void* const* d_in, const int* in_sizes, int n_in,
                              void* d_out, int out_size, void* d_ws, size_t ws_size,
                              hipStream_t stream) {
    const float* x     = (const float*)d_in[0];
    const int*   conn  = (const int*)d_in[1];
    const int*   opidx = (const int*)d_in[2];
    float*       out   = (float*)d_out;
    int*         connT = (int*)d_ws;    // 64 x 4096 ints = 1 MiB

    connT_kernel<<<OUT_F / 64, 256, 0, stream>>>(conn, connT);

    const int nblocks = (BATCH / BT) * (OUT_F / OGRP);   // 64 * 8 = 512
    agg_kernel<<<nblocks, NTHR, 0, stream>>>(x, connT, opidx, out);
}

// Round 8
// 27.937 us; speedup vs baseline: 1.2821x; 1.2821x over previous
//
#include <hip/hip_runtime.h>

#define IN_F   4096
#define OUT_F  4096
#define BATCH  512
#define NCONN  64
#define BT     4       // batch rows per block
#define OGRP   1024    // output features per block (1 per thread)
#define NTHR   1024

typedef _Float16 h4v __attribute__((ext_vector_type(4)));   // 8 B LDS granule

// ---------------- Kernel 1: connT[k][o] = conn[o][k] ----------------
__global__ __launch_bounds__(256) void connT_kernel(const int* __restrict__ conn,
                                                    int* __restrict__ connT) {
    __shared__ int tile[64][65];
    const int o0 = blockIdx.x * 64;
    const int tx = threadIdx.x & 63;
    const int ty = threadIdx.x >> 6;   // 0..3
#pragma unroll
    for (int r = 0; r < 16; ++r) {
        const int row = ty * 16 + r;                  // o-local
        tile[row][tx] = conn[(size_t)(o0 + row) * NCONN + tx];
    }
    __syncthreads();
#pragma unroll
    for (int r = 0; r < 16; ++r) {
        const int k = ty * 16 + r;
        connT[(size_t)k * OUT_F + o0 + tx] = tile[tx][k];
    }
}

// ---------------- Kernel 2: LDS-staged gather + reduce ----------------
// Block: 4 batch rows x 1024 o's. x-slice (4096 j x 4 b) fp16 in 32 KB LDS.
// 512 blocks -> 2 blocks/CU, 32 waves/CU.
__global__ __launch_bounds__(NTHR, 8) void agg_kernel(const float* __restrict__ x,
                                                      const int* __restrict__ connT,
                                                      const int* __restrict__ opidx,
                                                      float* __restrict__ out) {
    __shared__ alignas(16) _Float16 xs[IN_F * BT];   // [j][b], 32 KB

    // 512 blocks = 128 b-tiles x 4 o-groups. HW round-robins bid->XCD (bid&7);
    // map so the 4 o-group blocks of one b-tile share an XCD: per-XCD x
    // footprint = 64 rows x 16 KB = 1 MB (L2-resident), staged 4x from L2.
    const int bid   = blockIdx.x;
    const int btile = (bid & 7) * 16 + (bid >> 5);   // 0..127
    const int og    = (bid >> 3) & 3;                // 0..3
    const int o0    = og * OGRP;
    const int b0    = btile * BT;
    const int t     = threadIdx.x;

    // ---- stage x slice -> LDS fp16 [j][b] ----
    // wave covers 4 rows x 16 consecutive j (64 B per row -> 4 full lines).
    const int bb   = t & 3;
    const int joff = t >> 2;                         // 0..255
    const float* __restrict__ xrow = x + (size_t)(b0 + bb) * IN_F;
#pragma unroll 4
    for (int it = 0; it < 16; ++it) {
        const int j = it * 256 + joff;
        xs[j * BT + bb] = (_Float16)xrow[j];
    }
    __syncthreads();

    // ---- gather + reduce: one o per thread, 8-deep pipeline ----
    const int o = o0 + t;
    const int* __restrict__ cp = connT + o;

    float s0 = 0.f, s1 = 0.f, s2 = 0.f, s3 = 0.f;
    float mx0 = -__builtin_inff(), mx1 = mx0, mx2 = mx0, mx3 = mx0;
    float mn0 =  __builtin_inff(), mn1 = mn0, mn2 = mn0, mn3 = mn0;

    int idx[8];
#pragma unroll
    for (int q = 0; q < 8; ++q) idx[q] = cp[(size_t)q * OUT_F];

    for (int kb = 0; kb < NCONN; kb += 8) {
        h4v v[8];
#pragma unroll
        for (int q = 0; q < 8; ++q)
            v[q] = *reinterpret_cast<const h4v*>(&xs[idx[q] * BT]);   // ds_read_b64
        if (kb + 8 < NCONN) {
#pragma unroll
            for (int q = 0; q < 8; ++q) idx[q] = cp[(size_t)(kb + 8 + q) * OUT_F];
        }
#pragma unroll
        for (int q = 0; q < 8; ++q) {
            const float f0 = (float)v[q][0];
            const float f1 = (float)v[q][1];
            const float f2 = (float)v[q][2];
            const float f3 = (float)v[q][3];
            s0 += f0;  s1 += f1;  s2 += f2;  s3 += f3;
            mx0 = fmaxf(mx0, f0); mx1 = fmaxf(mx1, f1);
            mx2 = fmaxf(mx2, f2); mx3 = fmaxf(mx3, f3);
            mn0 = fminf(mn0, f0); mn1 = fminf(mn1, f1);
            mn2 = fminf(mn2, f2); mn3 = fminf(mn3, f3);
        }
    }

    // ---- epilogue: scalar NT stores, coalesced along o ----
    const int op = opidx[o];
    float* __restrict__ fwd  = out;                          // (B, OUT_F)
    float* __restrict__ outp = out + (size_t)BATCH * OUT_F;  // (B, 4, OUT_F)

    const float sv[4] = {s0, s1, s2, s3};
    const float xv[4] = {mx0, mx1, mx2, mx3};
    const float nv[4] = {mn0, mn1, mn2, mn3};
#pragma unroll
    for (int i = 0; i < 4; ++i) {
        const float ss = sv[i];
        const float mm = ss * 0.015625f;
        const float hx = xv[i];
        const float ln = nv[i];
        const float fw = (op == 0) ? mm : (op == 1) ? ss : (op == 2) ? hx : ln;
        const size_t rowO = (size_t)(b0 + i) * (4 * OUT_F) + o;
        __builtin_nontemporal_store(fw, fwd + (size_t)(b0 + i) * OUT_F + o);
        __builtin_nontemporal_store(mm, outp + rowO);
        __builtin_nontemporal_store(ss, outp + rowO + OUT_F);
        __builtin_nontemporal_store(hx, outp + rowO + 2 * OUT_F);
        __builtin_nontemporal_store(ln, outp + rowO + 3 * OUT_F);
    }
}

extern "C" void kernel_launch(void* const* d_in, const int* in_sizes, int n_in,
                              void* d_out, int out_size, void* d_ws, size_t ws_size,
                              hipStream_t stream) {
    const float* x     = (const float*)d_in[0];
    const int*   conn  = (const int*)d_in[1];
    const int*   opidx = (const int*)d_in[2];
    float*       out   = (float*)d_out;
    int*         connT = (int*)d_ws;    // 64 x 4096 ints = 1 MiB

    connT_kernel<<<OUT_F / 64, 256, 0, stream>>>(conn, connT);

    const int nblocks = (BATCH / BT) * (OUT_F / OGRP);   // 128 * 4 = 512
    agg_kernel<<<nblocks, NTHR, 0, stream>>>(x, connT, opidx, out);
}